// Round 10
// baseline (338.635 us; speedup 1.0000x reference)
//
#include <hip/hip_runtime.h>
#include <math.h>

#define N_NODES 50000
#define N_EDGES 800000
#define K_IN    128
#define HC      256    // H*C = 8*32
#define NCOLS   768    // 3 * HC fused GEMM outputs: [xl | xr | res]

typedef __bf16 bf16x8 __attribute__((ext_vector_type(8)));
typedef float  f32x4  __attribute__((ext_vector_type(4)));

__device__ inline ushort f32_to_bf16(float f)
{
    union { float f; uint u; } c; c.f = f;
    uint r = c.u + 0x7fff + ((c.u >> 16) & 1);   // RNE
    return (ushort)(r >> 16);
}
__device__ inline float bf16_to_f32(ushort u)
{
    union { uint u; float f; } c; c.u = (uint)u << 16;
    return c.f;
}
// 8 packed bf16 (memory order) -> 8 floats : 4 shl + 4 and
__device__ inline void bf8_to_f8(uint4 u, float* f)
{
    f[0] = __uint_as_float(u.x << 16);
    f[1] = __uint_as_float(u.x & 0xffff0000u);
    f[2] = __uint_as_float(u.y << 16);
    f[3] = __uint_as_float(u.y & 0xffff0000u);
    f[4] = __uint_as_float(u.z << 16);
    f[5] = __uint_as_float(u.z & 0xffff0000u);
    f[6] = __uint_as_float(u.w << 16);
    f[7] = __uint_as_float(u.w & 0xffff0000u);
}

// ---------------------------------------------------------------------------
// x [N][128] fp32 -> Xh/Xl [N][128] bf16 (hi + residual-lo), done ONCE
// ---------------------------------------------------------------------------
__global__ void convert_x_kernel(const float* __restrict__ x,
                                 ushort* __restrict__ Xh, ushort* __restrict__ Xl)
{
    int t = blockIdx.x * 256 + threadIdx.x;     // 4 elems per thread
    if (t >= N_NODES * (K_IN / 4)) return;
    float4 v = reinterpret_cast<const float4*>(x)[t];
    ushort h0 = f32_to_bf16(v.x), h1 = f32_to_bf16(v.y);
    ushort h2 = f32_to_bf16(v.z), h3 = f32_to_bf16(v.w);
    ushort l0 = f32_to_bf16(v.x - bf16_to_f32(h0));
    ushort l1 = f32_to_bf16(v.y - bf16_to_f32(h1));
    ushort l2 = f32_to_bf16(v.z - bf16_to_f32(h2));
    ushort l3 = f32_to_bf16(v.w - bf16_to_f32(h3));
    reinterpret_cast<uint2*>(Xh)[t] =
        make_uint2((uint)h0 | ((uint)h1 << 16), (uint)h2 | ((uint)h3 << 16));
    reinterpret_cast<uint2*>(Xl)[t] =
        make_uint2((uint)l0 | ((uint)l1 << 16), (uint)l2 | ((uint)l3 << 16));
}

// ---------------------------------------------------------------------------
// Weight prep: W_l|W_r|Wp [128,256] fp32 -> Wt_hi/Wt_lo [768][128] bf16
// ---------------------------------------------------------------------------
__global__ void convert_w_kernel(const float* __restrict__ Wl,
                                 const float* __restrict__ Wr,
                                 const float* __restrict__ Wp,
                                 ushort* __restrict__ Wt_hi,
                                 ushort* __restrict__ Wt_lo)
{
    int t = blockIdx.x * 256 + threadIdx.x;
    if (t >= NCOLS * K_IN) return;
    int n = t >> 7, k = t & 127;
    const float* W = (n < 256) ? Wl : (n < 512) ? Wr : Wp;
    int nn = n & 255;
    float v = W[(size_t)k * HC + nn];
    ushort h = f32_to_bf16(v);
    Wt_hi[t] = h;
    Wt_lo[t] = f32_to_bf16(v - bf16_to_f32(h));
}

// ---------------------------------------------------------------------------
// Split-bf16 MFMA GEMM. 128x128 tile, BK=64, 4 waves of 64x64.
// cols 0..511  -> xfb bf16 [N][512]  (xl | xr)
// cols 512..767-> res fp32 [N][256]  (+bp)
// ---------------------------------------------------------------------------
__global__ __launch_bounds__(256, 2) void gemm_mfma_kernel(
    const ushort* __restrict__ Xh, const ushort* __restrict__ Xl,
    const ushort* __restrict__ Wt_hi, const ushort* __restrict__ Wt_lo,
    const float* __restrict__ bp,
    ushort* __restrict__ xfb, float* __restrict__ res)
{
    __shared__ ushort Ah[128 * 64], Al[128 * 64], Bh[128 * 64], Bl[128 * 64];

    const int bm = blockIdx.x;
    const int bn = blockIdx.y;          // 0..5, N-tile of 128
    const int nbase = bn * 128;
    const int tid = threadIdx.x;
    const int lane = tid & 63;
    const int w = tid >> 6;
    const int wr = w >> 1, wc = w & 1;
    const int fr = lane & 15;
    const int kg = lane >> 4;

    f32x4 acc[4][4];
#pragma unroll
    for (int mi = 0; mi < 4; ++mi)
#pragma unroll
        for (int ni = 0; ni < 4; ++ni) acc[mi][ni] = (f32x4)0.f;

#pragma unroll
    for (int ks = 0; ks < 2; ++ks) {
        const int k0 = ks * 64;
        // ---- stage A: pure uint2 copies, XOR-swizzled LDS ----
#pragma unroll
        for (int i = 0; i < 8; ++i) {
            int f = tid + i * 256;
            int r = f >> 4, q = f & 15;
            int grow = bm * 128 + r;
            uint2 hv = make_uint2(0u, 0u), lv = make_uint2(0u, 0u);
            if (grow < N_NODES) {
                size_t g = (size_t)grow * K_IN + k0 + q * 4;
                hv = *reinterpret_cast<const uint2*>(&Xh[g]);
                lv = *reinterpret_cast<const uint2*>(&Xl[g]);
            }
            int off = r * 64 + ((q * 4) ^ ((r & 7) << 3));
            *reinterpret_cast<uint2*>(&Ah[off]) = hv;
            *reinterpret_cast<uint2*>(&Al[off]) = lv;
        }
        // ---- stage B ----
#pragma unroll
        for (int i = 0; i < 8; ++i) {
            int f = tid + i * 256;
            int n = f >> 4, q = f & 15;
            size_t g = (size_t)(nbase + n) * K_IN + k0 + q * 4;
            uint2 hv = *reinterpret_cast<const uint2*>(&Wt_hi[g]);
            uint2 lv = *reinterpret_cast<const uint2*>(&Wt_lo[g]);
            int off = n * 64 + ((q * 4) ^ ((n & 7) << 3));
            *reinterpret_cast<uint2*>(&Bh[off]) = hv;
            *reinterpret_cast<uint2*>(&Bl[off]) = lv;
        }
        __syncthreads();
#pragma unroll
        for (int kk = 0; kk < 2; ++kk) {
            const int kush = kk * 32 + kg * 8;
            bf16x8 ah[4], al[4], bh[4], blo[4];
#pragma unroll
            for (int mi = 0; mi < 4; ++mi) {
                int row = wr * 64 + mi * 16 + fr;
                int off = row * 64 + (kush ^ ((row & 7) << 3));
                ah[mi] = *reinterpret_cast<const bf16x8*>(&Ah[off]);
                al[mi] = *reinterpret_cast<const bf16x8*>(&Al[off]);
            }
#pragma unroll
            for (int ni = 0; ni < 4; ++ni) {
                int nrow = wc * 64 + ni * 16 + fr;
                int off = nrow * 64 + (kush ^ ((nrow & 7) << 3));
                bh[ni]  = *reinterpret_cast<const bf16x8*>(&Bh[off]);
                blo[ni] = *reinterpret_cast<const bf16x8*>(&Bl[off]);
            }
#pragma unroll
            for (int mi = 0; mi < 4; ++mi)
#pragma unroll
                for (int ni = 0; ni < 4; ++ni) {
                    acc[mi][ni] = __builtin_amdgcn_mfma_f32_16x16x32_bf16(ah[mi], bh[ni],  acc[mi][ni], 0, 0, 0);
                    acc[mi][ni] = __builtin_amdgcn_mfma_f32_16x16x32_bf16(al[mi], bh[ni],  acc[mi][ni], 0, 0, 0);
                    acc[mi][ni] = __builtin_amdgcn_mfma_f32_16x16x32_bf16(ah[mi], blo[ni], acc[mi][ni], 0, 0, 0);
                }
        }
        __syncthreads();
    }

    if (bn < 4) {
#pragma unroll
        for (int mi = 0; mi < 4; ++mi)
#pragma unroll
            for (int i = 0; i < 4; ++i) {
                int row = bm * 128 + wr * 64 + mi * 16 + kg * 4 + i;
                if (row >= N_NODES) continue;
#pragma unroll
                for (int ni = 0; ni < 4; ++ni) {
                    int col = nbase + wc * 64 + ni * 16 + fr;
                    xfb[(size_t)row * 512 + col] = f32_to_bf16(acc[mi][ni][i]);
                }
            }
    } else {
        float badd[4];
#pragma unroll
        for (int ni = 0; ni < 4; ++ni)
            badd[ni] = bp[nbase - 512 + wc * 64 + ni * 16 + fr];
#pragma unroll
        for (int mi = 0; mi < 4; ++mi)
#pragma unroll
            for (int i = 0; i < 4; ++i) {
                int row = bm * 128 + wr * 64 + mi * 16 + kg * 4 + i;
                if (row >= N_NODES) continue;
#pragma unroll
                for (int ni = 0; ni < 4; ++ni) {
                    int col = nbase - 512 + wc * 64 + ni * 16 + fr;
                    res[(size_t)row * 256 + col] = acc[mi][ni][i] + badd[ni];
                }
            }
    }
}

// ---------------------------------------------------------------------------
// CSR build: zero -> histogram -> 3-kernel scan -> scatter
// ---------------------------------------------------------------------------
#define SCAN_CH 1024
#define SCAN_NB ((N_NODES + SCAN_CH - 1) / SCAN_CH)   // 49

__global__ void zero_int_kernel(int* __restrict__ p, int n)
{
    int i = blockIdx.x * blockDim.x + threadIdx.x;
    if (i < n) p[i] = 0;
}

__global__ void hist_kernel(const int* __restrict__ ei, int* __restrict__ deg)
{
    int e = blockIdx.x * blockDim.x + threadIdx.x;
    if (e < N_EDGES) atomicAdd(&deg[ei[N_EDGES + e]], 1);
}

__device__ inline int wave_incl_scan(int v, int lane)
{
#pragma unroll
    for (int off = 1; off < 64; off <<= 1) {
        int t = __shfl_up(v, off, 64);
        if (lane >= off) v += t;
    }
    return v;
}

__device__ inline int wave_sum(int v)
{
#pragma unroll
    for (int off = 1; off < 64; off <<= 1) v += __shfl_xor(v, off, 64);
    return v;
}

__global__ __launch_bounds__(1024) void scan_partial_kernel(
    const int* __restrict__ deg, int* __restrict__ bsum)
{
    __shared__ int wsum[16];
    int i = blockIdx.x * SCAN_CH + threadIdx.x;
    int lane = threadIdx.x & 63, wid = threadIdx.x >> 6;
    int v = (i < N_NODES) ? deg[i] : 0;
    int s = wave_sum(v);
    if (lane == 0) wsum[wid] = s;
    __syncthreads();
    if (threadIdx.x == 0) {
        int t = 0;
#pragma unroll
        for (int k = 0; k < 16; ++k) t += wsum[k];
        bsum[blockIdx.x] = t;
    }
}

__global__ void scan_base_kernel(const int* __restrict__ bsum,
                                 int* __restrict__ bbase, int* __restrict__ offs)
{
    int lane = threadIdx.x;   // 64 threads
    int v = (lane < SCAN_NB) ? bsum[lane] : 0;
    int inc = wave_incl_scan(v, lane);
    if (lane < SCAN_NB) bbase[lane] = inc - v;
    if (lane == 63) offs[N_NODES] = inc;
}

__global__ __launch_bounds__(1024) void scan_final_kernel(
    const int* __restrict__ deg, const int* __restrict__ bbase,
    int* __restrict__ offs, int* __restrict__ cursor)
{
    __shared__ int wsum[16];
    int i = blockIdx.x * SCAN_CH + threadIdx.x;
    int lane = threadIdx.x & 63, wid = threadIdx.x >> 6;
    int v = (i < N_NODES) ? deg[i] : 0;
    int inc = wave_incl_scan(v, lane);
    if (lane == 63) wsum[wid] = inc;
    __syncthreads();
    if (wid == 0) {
        int wv = (lane < 16) ? wsum[lane] : 0;
        int ws = wave_incl_scan(wv, lane);
        if (lane < 16) wsum[lane] = ws;
    }
    __syncthreads();
    int wbase = wid ? wsum[wid - 1] : 0;
    int excl = bbase[blockIdx.x] + wbase + inc - v;
    if (i < N_NODES) { offs[i] = excl; cursor[i] = excl; }
}

__global__ void scatter_kernel(const int* __restrict__ ei,
                               int* __restrict__ cursor, int* __restrict__ csr)
{
    int e = blockIdx.x * blockDim.x + threadIdx.x;
    if (e < N_EDGES) {
        int s = ei[e];
        int d = ei[N_EDGES + e];
        int pos = atomicAdd(&cursor[d], 1);
        csr[pos] = s;
    }
}

// ---------------------------------------------------------------------------
// Aggregation v4: half-wave layout. lane = (half<<5)|c8; lane owns 8 channels
// (c8*8..c8*8+7) of 256; lanes 0-31 process edge A, 32-63 edge B (2 edges per
// wave iteration, one uint4 gather each). A head's 32 channels live in a
// 4-lane quad -> score reduce = 2 quad_perm DPP ops (no LDS crossbar).
// Fixed-m softmax (m = first edge's score, cancels in normalization).
// ---------------------------------------------------------------------------
__device__ inline float dpp_add_xor1(float p)
{
    int q = __builtin_amdgcn_update_dpp(0, __float_as_int(p), 0xB1, 0xF, 0xF, true);
    return p + __int_as_float(q);
}
__device__ inline float dpp_add_xor2(float p)
{
    int q = __builtin_amdgcn_update_dpp(0, __float_as_int(p), 0x4E, 0xF, 0xF, true);
    return p + __int_as_float(q);
}

__device__ inline float score8(const float* v, const float* xr8,
                               const float* a1, const float* a2)
{
    float p = 0.f;
#pragma unroll
    for (int i = 0; i < 8; ++i) {
        float t = v[i] + xr8[i];
        p = fmaf(a1[i], t, p);
        p = fmaf(a2[i], fabsf(t), p);
    }
    p = dpp_add_xor1(p);   // sum over quad -> full 32-channel head score
    p = dpp_add_xor2(p);
    return p;
}

__global__ __launch_bounds__(256) void gat_agg_kernel(
    const ushort* __restrict__ xfb, const float* __restrict__ res,
    const int* __restrict__ offs, const int* __restrict__ csr,
    const float* __restrict__ att, const float* __restrict__ bias,
    float* __restrict__ out)
{
    const int lane = threadIdx.x & 63;
    const int wid = threadIdx.x >> 6;
    const int node = blockIdx.x * 4 + wid;
    if (node >= N_NODES) return;

    const int c8 = lane & 31;       // 8-channel chunk id (head = c8>>2)
    const int half = lane >> 5;     // 0: edge A, 1: edge B

    // attention vector chunk, leaky folded: p = sum 0.6a*t + 0.4a*|t|
    float a1[8], a2[8], xr8[8];
    {
        float4 t0 = reinterpret_cast<const float4*>(att)[c8 * 2];
        float4 t1 = reinterpret_cast<const float4*>(att)[c8 * 2 + 1];
        float av[8] = {t0.x, t0.y, t0.z, t0.w, t1.x, t1.y, t1.z, t1.w};
#pragma unroll
        for (int i = 0; i < 8; ++i) { a1[i] = 0.6f * av[i]; a2[i] = 0.4f * av[i]; }
    }
    {
        uint4 u = *reinterpret_cast<const uint4*>(&xfb[(uint)node * 512u + 256u + (uint)c8 * 8u]);
        bf8_to_f8(u, xr8);
    }

    const int e0 = offs[node];
    const int e1 = offs[node + 1];

    float m = 0.f, d = 0.f;
    float acc[8] = {0.f, 0.f, 0.f, 0.f, 0.f, 0.f, 0.f, 0.f};

    int e = e0;
    if (e < e1) {                    // first edge: defines m; counted in lo half
        int s = csr[e];
        uint4 u = *reinterpret_cast<const uint4*>(&xfb[(uint)s * 512u + (uint)c8 * 8u]);
        float v[8]; bf8_to_f8(u, v);
        m = score8(v, xr8, a1, a2);
        float w0 = (half == 0) ? 1.f : 0.f;
        d = w0;
#pragma unroll
        for (int i = 0; i < 8; ++i) acc[i] = v[i] * w0;
        ++e;
    }
    for (; e + 1 < e1; e += 2) {     // 2 edges per iteration (one per half)
        int sA = csr[e], sB = csr[e + 1];
        int s = half ? sB : sA;
        uint4 u = *reinterpret_cast<const uint4*>(&xfb[(uint)s * 512u + (uint)c8 * 8u]);
        float v[8]; bf8_to_f8(u, v);
        float p = score8(v, xr8, a1, a2);
        float w = __expf(p - m);
        d += w;
#pragma unroll
        for (int i = 0; i < 8; ++i) acc[i] = fmaf(w, v[i], acc[i]);
    }
    if (e < e1) {                    // odd tail: both halves load it, hi half zeroed
        int s = csr[e];
        uint4 u = *reinterpret_cast<const uint4*>(&xfb[(uint)s * 512u + (uint)c8 * 8u]);
        float v[8]; bf8_to_f8(u, v);
        float p = score8(v, xr8, a1, a2);
        float w = (half == 0) ? __expf(p - m) : 0.f;
        d += w;
#pragma unroll
        for (int i = 0; i < 8; ++i) acc[i] = fmaf(w, v[i], acc[i]);
    }

    // combine the two halves (once per node)
    d += __shfl_xor(d, 32, 64);
#pragma unroll
    for (int i = 0; i < 8; ++i) acc[i] += __shfl_xor(acc[i], 32, 64);

    if (half == 0) {
        float inv = 1.f / fmaxf(d, 1e-16f);
        float4 b0 = reinterpret_cast<const float4*>(bias)[c8 * 2];
        float4 b1 = reinterpret_cast<const float4*>(bias)[c8 * 2 + 1];
        float4 r0 = reinterpret_cast<const float4*>(res)[(uint)node * 64u + c8 * 2];
        float4 r1 = reinterpret_cast<const float4*>(res)[(uint)node * 64u + c8 * 2 + 1];
        float bv[8] = {b0.x, b0.y, b0.z, b0.w, b1.x, b1.y, b1.z, b1.w};
        float rv[8] = {r0.x, r0.y, r0.z, r0.w, r1.x, r1.y, r1.z, r1.w};
        float o[8];
#pragma unroll
        for (int i = 0; i < 8; ++i) {
            float t = fmaf(acc[i], inv, bv[i] + rv[i]);
            o[i] = 0.5f * t * (1.f + erff(t * 0.70710678118654752f));
        }
        float4 o0 = make_float4(o[0], o[1], o[2], o[3]);
        float4 o1 = make_float4(o[4], o[5], o[6], o[7]);
        reinterpret_cast<float4*>(out)[(uint)node * 64u + c8 * 2] = o0;
        reinterpret_cast<float4*>(out)[(uint)node * 64u + c8 * 2 + 1] = o1;
    }
}

// ---------------------------------------------------------------------------
extern "C" void kernel_launch(void* const* d_in, const int* in_sizes, int n_in,
                              void* d_out, int out_size, void* d_ws, size_t ws_size,
                              hipStream_t stream)
{
    const float* x    = (const float*)d_in[0];
    const int*   ei   = (const int*)d_in[1];
    const float* Wl   = (const float*)d_in[2];
    const float* Wr   = (const float*)d_in[3];
    const float* att  = (const float*)d_in[4];
    const float* bias = (const float*)d_in[5];
    const float* Wp   = (const float*)d_in[6];
    const float* bp   = (const float*)d_in[7];
    float* out = (float*)d_out;

    // workspace layout
    ushort* xfb   = (ushort*)d_ws;                               // N*512 bf16
    float*  res   = (float*)(xfb + (size_t)N_NODES * 512);       // N*256 fp32
    ushort* Xh    = (ushort*)(res + (size_t)N_NODES * 256);      // N*128 bf16
    ushort* Xl    = Xh + (size_t)N_NODES * K_IN;                 // N*128 bf16
    ushort* Wt_hi = Xl + (size_t)N_NODES * K_IN;                 // 768*128
    ushort* Wt_lo = Wt_hi + NCOLS * K_IN;
    int* deg    = (int*)(Wt_lo + NCOLS * K_IN);                  // N
    int* offs   = deg + N_NODES;                                 // N+1
    int* cursor = offs + N_NODES + 1;                            // N
    int* csr    = cursor + N_NODES;                              // E
    int* bsum   = csr + N_EDGES;                                 // SCAN_NB
    int* bbase  = bsum + SCAN_NB;                                // SCAN_NB

    hipLaunchKernelGGL(convert_x_kernel, dim3((N_NODES * (K_IN / 4) + 255) / 256), dim3(256), 0, stream,
                       x, Xh, Xl);
    hipLaunchKernelGGL(convert_w_kernel, dim3((NCOLS * K_IN + 255) / 256), dim3(256), 0, stream,
                       Wl, Wr, Wp, Wt_hi, Wt_lo);
    hipLaunchKernelGGL(zero_int_kernel, dim3((N_NODES + 255) / 256), dim3(256), 0, stream,
                       deg, N_NODES);
    hipLaunchKernelGGL(hist_kernel, dim3((N_EDGES + 255) / 256), dim3(256), 0, stream,
                       ei, deg);
    hipLaunchKernelGGL(scan_partial_kernel, dim3(SCAN_NB), dim3(1024), 0, stream,
                       deg, bsum);
    hipLaunchKernelGGL(scan_base_kernel, dim3(1), dim3(64), 0, stream,
                       bsum, bbase, offs);
    hipLaunchKernelGGL(scan_final_kernel, dim3(SCAN_NB), dim3(1024), 0, stream,
                       deg, bbase, offs, cursor);
    hipLaunchKernelGGL(scatter_kernel, dim3((N_EDGES + 255) / 256), dim3(256), 0, stream,
                       ei, cursor, csr);
    hipLaunchKernelGGL(gemm_mfma_kernel, dim3((N_NODES + 127) / 128, 6), dim3(256), 0, stream,
                       Xh, Xl, Wt_hi, Wt_lo, bp, xfb, res);
    hipLaunchKernelGGL(gat_agg_kernel, dim3((N_NODES + 3) / 4), dim3(256), 0, stream,
                       xfb, res, offs, csr, att, bias, out);
}

// Round 11
// 321.875 us; speedup vs baseline: 1.0521x; 1.0521x over previous
//
#include <hip/hip_runtime.h>
#include <math.h>

#define N_NODES 50000
#define N_EDGES 800000
#define K_IN    128
#define HC      256    // H*C = 8*32
#define NCOLS   768    // 3 * HC fused GEMM outputs: [xl | xr | res]

typedef __bf16 bf16x8 __attribute__((ext_vector_type(8)));
typedef float  f32x4  __attribute__((ext_vector_type(4)));

__device__ inline ushort f32_to_bf16(float f)
{
    union { float f; uint u; } c; c.f = f;
    uint r = c.u + 0x7fff + ((c.u >> 16) & 1);   // RNE
    return (ushort)(r >> 16);
}
__device__ inline float bf16_to_f32(ushort u)
{
    union { uint u; float f; } c; c.u = (uint)u << 16;
    return c.f;
}
// 4 packed bf16 (memory order) -> float4 : 2 shl + 2 and
__device__ inline float4 bf4_to_f4(uint2 u)
{
    float4 r;
    r.x = __uint_as_float(u.x << 16);
    r.y = __uint_as_float(u.x & 0xffff0000u);
    r.z = __uint_as_float(u.y << 16);
    r.w = __uint_as_float(u.y & 0xffff0000u);
    return r;
}

// ---------------------------------------------------------------------------
// x [N][128] fp32 -> Xh/Xl [N][128] bf16 (hi + residual-lo), done ONCE
// ---------------------------------------------------------------------------
__global__ void convert_x_kernel(const float* __restrict__ x,
                                 ushort* __restrict__ Xh, ushort* __restrict__ Xl)
{
    int t = blockIdx.x * 256 + threadIdx.x;     // 4 elems per thread
    if (t >= N_NODES * (K_IN / 4)) return;
    float4 v = reinterpret_cast<const float4*>(x)[t];
    ushort h0 = f32_to_bf16(v.x), h1 = f32_to_bf16(v.y);
    ushort h2 = f32_to_bf16(v.z), h3 = f32_to_bf16(v.w);
    ushort l0 = f32_to_bf16(v.x - bf16_to_f32(h0));
    ushort l1 = f32_to_bf16(v.y - bf16_to_f32(h1));
    ushort l2 = f32_to_bf16(v.z - bf16_to_f32(h2));
    ushort l3 = f32_to_bf16(v.w - bf16_to_f32(h3));
    reinterpret_cast<uint2*>(Xh)[t] =
        make_uint2((uint)h0 | ((uint)h1 << 16), (uint)h2 | ((uint)h3 << 16));
    reinterpret_cast<uint2*>(Xl)[t] =
        make_uint2((uint)l0 | ((uint)l1 << 16), (uint)l2 | ((uint)l3 << 16));
}

// ---------------------------------------------------------------------------
// Weight prep: W_l|W_r|Wp [128,256] fp32 -> Wt_hi/Wt_lo [768][128] bf16
// ---------------------------------------------------------------------------
__global__ void convert_w_kernel(const float* __restrict__ Wl,
                                 const float* __restrict__ Wr,
                                 const float* __restrict__ Wp,
                                 ushort* __restrict__ Wt_hi,
                                 ushort* __restrict__ Wt_lo)
{
    int t = blockIdx.x * 256 + threadIdx.x;
    if (t >= NCOLS * K_IN) return;
    int n = t >> 7, k = t & 127;
    const float* W = (n < 256) ? Wl : (n < 512) ? Wr : Wp;
    int nn = n & 255;
    float v = W[(size_t)k * HC + nn];
    ushort h = f32_to_bf16(v);
    Wt_hi[t] = h;
    Wt_lo[t] = f32_to_bf16(v - bf16_to_f32(h));
}

// ---------------------------------------------------------------------------
// Split-bf16 MFMA GEMM. 128x128 tile, BK=64, 4 waves of 64x64.
// cols 0..511  -> xfb  bf16 [N][512]  (xl | xr)
// cols 512..767-> resb bf16 [N][256]  (+bp)   [bf16 now: -25MB write]
// ---------------------------------------------------------------------------
__global__ __launch_bounds__(256, 2) void gemm_mfma_kernel(
    const ushort* __restrict__ Xh, const ushort* __restrict__ Xl,
    const ushort* __restrict__ Wt_hi, const ushort* __restrict__ Wt_lo,
    const float* __restrict__ bp,
    ushort* __restrict__ xfb, ushort* __restrict__ resb)
{
    __shared__ ushort Ah[128 * 64], Al[128 * 64], Bh[128 * 64], Bl[128 * 64];

    const int bm = blockIdx.x;
    const int bn = blockIdx.y;          // 0..5, N-tile of 128
    const int nbase = bn * 128;
    const int tid = threadIdx.x;
    const int lane = tid & 63;
    const int w = tid >> 6;
    const int wr = w >> 1, wc = w & 1;
    const int fr = lane & 15;
    const int kg = lane >> 4;

    f32x4 acc[4][4];
#pragma unroll
    for (int mi = 0; mi < 4; ++mi)
#pragma unroll
        for (int ni = 0; ni < 4; ++ni) acc[mi][ni] = (f32x4)0.f;

#pragma unroll
    for (int ks = 0; ks < 2; ++ks) {
        const int k0 = ks * 64;
        // ---- stage A: pure uint2 copies, XOR-swizzled LDS ----
#pragma unroll
        for (int i = 0; i < 8; ++i) {
            int f = tid + i * 256;
            int r = f >> 4, q = f & 15;
            int grow = bm * 128 + r;
            uint2 hv = make_uint2(0u, 0u), lv = make_uint2(0u, 0u);
            if (grow < N_NODES) {
                size_t g = (size_t)grow * K_IN + k0 + q * 4;
                hv = *reinterpret_cast<const uint2*>(&Xh[g]);
                lv = *reinterpret_cast<const uint2*>(&Xl[g]);
            }
            int off = r * 64 + ((q * 4) ^ ((r & 7) << 3));
            *reinterpret_cast<uint2*>(&Ah[off]) = hv;
            *reinterpret_cast<uint2*>(&Al[off]) = lv;
        }
        // ---- stage B ----
#pragma unroll
        for (int i = 0; i < 8; ++i) {
            int f = tid + i * 256;
            int n = f >> 4, q = f & 15;
            size_t g = (size_t)(nbase + n) * K_IN + k0 + q * 4;
            uint2 hv = *reinterpret_cast<const uint2*>(&Wt_hi[g]);
            uint2 lv = *reinterpret_cast<const uint2*>(&Wt_lo[g]);
            int off = n * 64 + ((q * 4) ^ ((n & 7) << 3));
            *reinterpret_cast<uint2*>(&Bh[off]) = hv;
            *reinterpret_cast<uint2*>(&Bl[off]) = lv;
        }
        __syncthreads();
#pragma unroll
        for (int kk = 0; kk < 2; ++kk) {
            const int kush = kk * 32 + kg * 8;
            bf16x8 ah[4], al[4], bh[4], blo[4];
#pragma unroll
            for (int mi = 0; mi < 4; ++mi) {
                int row = wr * 64 + mi * 16 + fr;
                int off = row * 64 + (kush ^ ((row & 7) << 3));
                ah[mi] = *reinterpret_cast<const bf16x8*>(&Ah[off]);
                al[mi] = *reinterpret_cast<const bf16x8*>(&Al[off]);
            }
#pragma unroll
            for (int ni = 0; ni < 4; ++ni) {
                int nrow = wc * 64 + ni * 16 + fr;
                int off = nrow * 64 + (kush ^ ((nrow & 7) << 3));
                bh[ni]  = *reinterpret_cast<const bf16x8*>(&Bh[off]);
                blo[ni] = *reinterpret_cast<const bf16x8*>(&Bl[off]);
            }
#pragma unroll
            for (int mi = 0; mi < 4; ++mi)
#pragma unroll
                for (int ni = 0; ni < 4; ++ni) {
                    acc[mi][ni] = __builtin_amdgcn_mfma_f32_16x16x32_bf16(ah[mi], bh[ni],  acc[mi][ni], 0, 0, 0);
                    acc[mi][ni] = __builtin_amdgcn_mfma_f32_16x16x32_bf16(al[mi], bh[ni],  acc[mi][ni], 0, 0, 0);
                    acc[mi][ni] = __builtin_amdgcn_mfma_f32_16x16x32_bf16(ah[mi], blo[ni], acc[mi][ni], 0, 0, 0);
                }
        }
        __syncthreads();
    }

    if (bn < 4) {
#pragma unroll
        for (int mi = 0; mi < 4; ++mi)
#pragma unroll
            for (int i = 0; i < 4; ++i) {
                int row = bm * 128 + wr * 64 + mi * 16 + kg * 4 + i;
                if (row >= N_NODES) continue;
#pragma unroll
                for (int ni = 0; ni < 4; ++ni) {
                    int col = nbase + wc * 64 + ni * 16 + fr;
                    xfb[(size_t)row * 512 + col] = f32_to_bf16(acc[mi][ni][i]);
                }
            }
    } else {
        float badd[4];
#pragma unroll
        for (int ni = 0; ni < 4; ++ni)
            badd[ni] = bp[nbase - 512 + wc * 64 + ni * 16 + fr];
#pragma unroll
        for (int mi = 0; mi < 4; ++mi)
#pragma unroll
            for (int i = 0; i < 4; ++i) {
                int row = bm * 128 + wr * 64 + mi * 16 + kg * 4 + i;
                if (row >= N_NODES) continue;
#pragma unroll
                for (int ni = 0; ni < 4; ++ni) {
                    int col = nbase - 512 + wc * 64 + ni * 16 + fr;
                    resb[(size_t)row * 256 + col] = f32_to_bf16(acc[mi][ni][i] + badd[ni]);
                }
            }
    }
}

// ---------------------------------------------------------------------------
// CSR build: zero -> histogram -> 3-kernel scan -> scatter
// ---------------------------------------------------------------------------
#define SCAN_CH 1024
#define SCAN_NB ((N_NODES + SCAN_CH - 1) / SCAN_CH)   // 49

__global__ void zero_int_kernel(int* __restrict__ p, int n)
{
    int i = blockIdx.x * blockDim.x + threadIdx.x;
    if (i < n) p[i] = 0;
}

__global__ void hist_kernel(const int* __restrict__ ei, int* __restrict__ deg)
{
    int e = blockIdx.x * blockDim.x + threadIdx.x;
    if (e < N_EDGES) atomicAdd(&deg[ei[N_EDGES + e]], 1);
}

__device__ inline int wave_incl_scan(int v, int lane)
{
#pragma unroll
    for (int off = 1; off < 64; off <<= 1) {
        int t = __shfl_up(v, off, 64);
        if (lane >= off) v += t;
    }
    return v;
}

__device__ inline int wave_sum(int v)
{
#pragma unroll
    for (int off = 1; off < 64; off <<= 1) v += __shfl_xor(v, off, 64);
    return v;
}

__global__ __launch_bounds__(1024) void scan_partial_kernel(
    const int* __restrict__ deg, int* __restrict__ bsum)
{
    __shared__ int wsum[16];
    int i = blockIdx.x * SCAN_CH + threadIdx.x;
    int lane = threadIdx.x & 63, wid = threadIdx.x >> 6;
    int v = (i < N_NODES) ? deg[i] : 0;
    int s = wave_sum(v);
    if (lane == 0) wsum[wid] = s;
    __syncthreads();
    if (threadIdx.x == 0) {
        int t = 0;
#pragma unroll
        for (int k = 0; k < 16; ++k) t += wsum[k];
        bsum[blockIdx.x] = t;
    }
}

__global__ void scan_base_kernel(const int* __restrict__ bsum,
                                 int* __restrict__ bbase, int* __restrict__ offs)
{
    int lane = threadIdx.x;   // 64 threads
    int v = (lane < SCAN_NB) ? bsum[lane] : 0;
    int inc = wave_incl_scan(v, lane);
    if (lane < SCAN_NB) bbase[lane] = inc - v;
    if (lane == 63) offs[N_NODES] = inc;
}

__global__ __launch_bounds__(1024) void scan_final_kernel(
    const int* __restrict__ deg, const int* __restrict__ bbase,
    int* __restrict__ offs, int* __restrict__ cursor)
{
    __shared__ int wsum[16];
    int i = blockIdx.x * SCAN_CH + threadIdx.x;
    int lane = threadIdx.x & 63, wid = threadIdx.x >> 6;
    int v = (i < N_NODES) ? deg[i] : 0;
    int inc = wave_incl_scan(v, lane);
    if (lane == 63) wsum[wid] = inc;
    __syncthreads();
    if (wid == 0) {
        int wv = (lane < 16) ? wsum[lane] : 0;
        int ws = wave_incl_scan(wv, lane);
        if (lane < 16) wsum[lane] = ws;
    }
    __syncthreads();
    int wbase = wid ? wsum[wid - 1] : 0;
    int excl = bbase[blockIdx.x] + wbase + inc - v;
    if (i < N_NODES) { offs[i] = excl; cursor[i] = excl; }
}

__global__ void scatter_kernel(const int* __restrict__ ei,
                               int* __restrict__ cursor, int* __restrict__ csr)
{
    int e = blockIdx.x * blockDim.x + threadIdx.x;
    if (e < N_EDGES) {
        int s = ei[e];
        int d = ei[N_EDGES + e];
        int pos = atomicAdd(&cursor[d], 1);
        csr[pos] = s;
    }
}

// ---------------------------------------------------------------------------
// Aggregation (v3, measured-best 77.5us): one wave per node, lane owns 4
// channels; fixed-m softmax (m = first edge's score); leaky folded into att;
// 4-edge unroll. res read as bf16 now.
// ---------------------------------------------------------------------------
__device__ inline float escore(float4 v, float4 xrv, float4 a1, float4 a2)
{
    float x0 = v.x + xrv.x, x1 = v.y + xrv.y, x2 = v.z + xrv.z, x3 = v.w + xrv.w;
    float p = a1.x * x0 + a2.x * fabsf(x0);
    p = fmaf(a1.y, x1, p); p = fmaf(a2.y, fabsf(x1), p);
    p = fmaf(a1.z, x2, p); p = fmaf(a2.z, fabsf(x2), p);
    p = fmaf(a1.w, x3, p); p = fmaf(a2.w, fabsf(x3), p);
    p += __shfl_xor(p, 1, 64);
    p += __shfl_xor(p, 2, 64);
    p += __shfl_xor(p, 4, 64);
    return p;
}

__global__ __launch_bounds__(256) void gat_agg_kernel(
    const ushort* __restrict__ xfb, const ushort* __restrict__ resb,
    const int* __restrict__ offs, const int* __restrict__ csr,
    const float* __restrict__ att, const float* __restrict__ bias,
    float* __restrict__ out)
{
    const int lane = threadIdx.x & 63;
    const int wid = threadIdx.x >> 6;
    const int node = blockIdx.x * 4 + wid;
    if (node >= N_NODES) return;

    const uint2* __restrict__ xfb2 = reinterpret_cast<const uint2*>(xfb);
    const uint2* __restrict__ res2 = reinterpret_cast<const uint2*>(resb);
    const float4 attv = reinterpret_cast<const float4*>(att)[lane];
    float4 a1, a2;
    a1.x = 0.6f * attv.x; a1.y = 0.6f * attv.y; a1.z = 0.6f * attv.z; a1.w = 0.6f * attv.w;
    a2.x = 0.4f * attv.x; a2.y = 0.4f * attv.y; a2.z = 0.4f * attv.z; a2.w = 0.4f * attv.w;
    const float4 xrv = bf4_to_f4(xfb2[(uint)node * 128u + 64u + lane]);

    const int e0 = offs[node];
    const int e1 = offs[node + 1];

    float m = 0.f, d = 0.f;
    float4 acc = make_float4(0.f, 0.f, 0.f, 0.f);

    int e = e0;
    if (e < e1) {                       // first edge defines m (per head)
        int s = csr[e];
        float4 v = bf4_to_f4(xfb2[((uint)s << 7) + lane]);
        m = escore(v, xrv, a1, a2);
        d = 1.f;
        acc = v;
        ++e;
    }
    for (; e + 3 < e1; e += 4) {
        int s0 = csr[e], s1 = csr[e + 1], s2 = csr[e + 2], s3 = csr[e + 3];
        float4 v0 = bf4_to_f4(xfb2[((uint)s0 << 7) + lane]);
        float4 v1 = bf4_to_f4(xfb2[((uint)s1 << 7) + lane]);
        float4 v2 = bf4_to_f4(xfb2[((uint)s2 << 7) + lane]);
        float4 v3 = bf4_to_f4(xfb2[((uint)s3 << 7) + lane]);
        float p0 = escore(v0, xrv, a1, a2);
        float p1 = escore(v1, xrv, a1, a2);
        float p2 = escore(v2, xrv, a1, a2);
        float p3 = escore(v3, xrv, a1, a2);
        float w0 = __expf(p0 - m), w1 = __expf(p1 - m);
        float w2 = __expf(p2 - m), w3 = __expf(p3 - m);
        d += (w0 + w1) + (w2 + w3);
        acc.x = fmaf(w3, v3.x, fmaf(w2, v2.x, fmaf(w1, v1.x, fmaf(w0, v0.x, acc.x))));
        acc.y = fmaf(w3, v3.y, fmaf(w2, v2.y, fmaf(w1, v1.y, fmaf(w0, v0.y, acc.y))));
        acc.z = fmaf(w3, v3.z, fmaf(w2, v2.z, fmaf(w1, v1.z, fmaf(w0, v0.z, acc.z))));
        acc.w = fmaf(w3, v3.w, fmaf(w2, v2.w, fmaf(w1, v1.w, fmaf(w0, v0.w, acc.w))));
    }
    for (; e < e1; ++e) {
        int s0 = csr[e];
        float4 v0 = bf4_to_f4(xfb2[((uint)s0 << 7) + lane]);
        float p0 = escore(v0, xrv, a1, a2);
        float w0 = __expf(p0 - m);
        d += w0;
        acc.x = fmaf(w0, v0.x, acc.x);
        acc.y = fmaf(w0, v0.y, acc.y);
        acc.z = fmaf(w0, v0.z, acc.z);
        acc.w = fmaf(w0, v0.w, acc.w);
    }

    float inv = 1.f / fmaxf(d, 1e-16f);
    const float4 bv = reinterpret_cast<const float4*>(bias)[lane];
    const float4 rv = bf4_to_f4(res2[(uint)node * 64u + lane]);
    float4 o;
    o.x = acc.x * inv + bv.x + rv.x;
    o.y = acc.y * inv + bv.y + rv.y;
    o.z = acc.z * inv + bv.z + rv.z;
    o.w = acc.w * inv + bv.w + rv.w;
    o.x = 0.5f * o.x * (1.f + erff(o.x * 0.70710678118654752f));
    o.y = 0.5f * o.y * (1.f + erff(o.y * 0.70710678118654752f));
    o.z = 0.5f * o.z * (1.f + erff(o.z * 0.70710678118654752f));
    o.w = 0.5f * o.w * (1.f + erff(o.w * 0.70710678118654752f));
    reinterpret_cast<float4*>(out)[(uint)node * 64u + lane] = o;
}

// ---------------------------------------------------------------------------
extern "C" void kernel_launch(void* const* d_in, const int* in_sizes, int n_in,
                              void* d_out, int out_size, void* d_ws, size_t ws_size,
                              hipStream_t stream)
{
    const float* x    = (const float*)d_in[0];
    const int*   ei   = (const int*)d_in[1];
    const float* Wl   = (const float*)d_in[2];
    const float* Wr   = (const float*)d_in[3];
    const float* att  = (const float*)d_in[4];
    const float* bias = (const float*)d_in[5];
    const float* Wp   = (const float*)d_in[6];
    const float* bp   = (const float*)d_in[7];
    float* out = (float*)d_out;

    // workspace layout
    ushort* xfb   = (ushort*)d_ws;                               // N*512 bf16
    ushort* resb  = xfb + (size_t)N_NODES * 512;                 // N*256 bf16
    ushort* Xh    = resb + (size_t)N_NODES * 256;                // N*128 bf16
    ushort* Xl    = Xh + (size_t)N_NODES * K_IN;                 // N*128 bf16
    ushort* Wt_hi = Xl + (size_t)N_NODES * K_IN;                 // 768*128
    ushort* Wt_lo = Wt_hi + NCOLS * K_IN;
    int* deg    = (int*)(Wt_lo + NCOLS * K_IN);                  // N
    int* offs   = deg + N_NODES;                                 // N+1
    int* cursor = offs + N_NODES + 1;                            // N
    int* csr    = cursor + N_NODES;                              // E
    int* bsum   = csr + N_EDGES;                                 // SCAN_NB
    int* bbase  = bsum + SCAN_NB;                                // SCAN_NB

    hipLaunchKernelGGL(convert_x_kernel, dim3((N_NODES * (K_IN / 4) + 255) / 256), dim3(256), 0, stream,
                       x, Xh, Xl);
    hipLaunchKernelGGL(convert_w_kernel, dim3((NCOLS * K_IN + 255) / 256), dim3(256), 0, stream,
                       Wl, Wr, Wp, Wt_hi, Wt_lo);
    hipLaunchKernelGGL(zero_int_kernel, dim3((N_NODES + 255) / 256), dim3(256), 0, stream,
                       deg, N_NODES);
    hipLaunchKernelGGL(hist_kernel, dim3((N_EDGES + 255) / 256), dim3(256), 0, stream,
                       ei, deg);
    hipLaunchKernelGGL(scan_partial_kernel, dim3(SCAN_NB), dim3(1024), 0, stream,
                       deg, bsum);
    hipLaunchKernelGGL(scan_base_kernel, dim3(1), dim3(64), 0, stream,
                       bsum, bbase, offs);
    hipLaunchKernelGGL(scan_final_kernel, dim3(SCAN_NB), dim3(1024), 0, stream,
                       deg, bbase, offs, cursor);
    hipLaunchKernelGGL(scatter_kernel, dim3((N_EDGES + 255) / 256), dim3(256), 0, stream,
                       ei, cursor, csr);
    hipLaunchKernelGGL(gemm_mfma_kernel, dim3((N_NODES + 127) / 128, 6), dim3(256), 0, stream,
                       Xh, Xl, Wt_hi, Wt_lo, bp, xfb, resb);
    hipLaunchKernelGGL(gat_agg_kernel, dim3((N_NODES + 3) / 4), dim3(256), 0, stream,
                       xfb, resb, offs, csr, att, bias, out);
}